// Round 2
// baseline (277.820 us; speedup 1.0000x reference)
//
#include <hip/hip_runtime.h>
#include <hip/hip_bf16.h>
#include <cstdint>
#include <cstddef>

// Problem constants: T=1024, H=1024, I=512, E=16, K=4
#define T_TOK 1024
#define HDIM  1024
#define IDIM  512
#define NEXP  16
#define TOPK  4
#define CAP   1024   // max gathered entries per expert (mean 256, sigma ~15.5)

typedef __bf16 bf16;
typedef __attribute__((ext_vector_type(8))) __bf16 bf16x8;
typedef __attribute__((ext_vector_type(4))) __bf16 bf16x4;
typedef __attribute__((ext_vector_type(4))) float f32x4;

__device__ __forceinline__ void lds_load16(void* lds_dst, const void* g_src) {
  __builtin_amdgcn_global_load_lds(
      (__attribute__((address_space(1))) unsigned int*)(void*)(g_src),
      (__attribute__((address_space(3))) unsigned int*)(lds_dst),
      16, 0, 0);
}

// ---------------- prep ----------------

// One block, 1024 threads: scatter (t,k) -> per-expert entry lists, pad to 64.
__global__ void routing_kernel(const int* __restrict__ idx, const float* __restrict__ w,
                               int* __restrict__ etok, float* __restrict__ ew,
                               int* __restrict__ cntpad) {
  __shared__ int cnt[NEXP];
  const int t = threadIdx.x;
  if (t < NEXP) cnt[t] = 0;
  __syncthreads();
  if (t < T_TOK) {
#pragma unroll
    for (int k = 0; k < TOPK; ++k) {
      int e = idx[t * TOPK + k];
      float wk = w[t * TOPK + k];
      int slot = atomicAdd(&cnt[e], 1);
      if (slot < CAP) { etok[e * CAP + slot] = t; ew[e * CAP + slot] = wk; }
    }
  }
  __syncthreads();
  for (int e = 0; e < NEXP; ++e) {
    int c = cnt[e];
    int p = (c + 63) & ~63;
    if (p > CAP) p = CAP;
    for (int j = c + t; j < p; j += blockDim.x) { etok[e * CAP + j] = 0; ew[e * CAP + j] = 0.f; }
    if (t == 0) cntpad[e] = p;
  }
}

__global__ void cvt_kernel(const float* __restrict__ src, bf16* __restrict__ dst, int n4) {
  int i = blockIdx.x * blockDim.x + threadIdx.x;
  if (i >= n4) return;
  float4 v = ((const float4*)src)[i];
  bf16x4 o;
  o[0] = (bf16)v.x; o[1] = (bf16)v.y; o[2] = (bf16)v.z; o[3] = (bf16)v.w;
  ((bf16x4*)dst)[i] = o;
}

// ---------------- GEMM1 (sparse): rows = gathered tokens of expert e ----------------
// tile 64(entries) x 128(I-channels), K=H=1024. Computes gate AND up tiles,
// epilogue: hsc[entry, i] = silu(g)*u*weight  (bf16, packed per expert region).
// LDS xor-swizzle: logical k-chunk c (16B) of row r stored at chunk c^(r&7).

template <bool BBF>
__global__ __launch_bounds__(256, 2) void gemm1_kernel(
    const bf16* __restrict__ hid,     // [T,H] bf16
    const float* __restrict__ gup_f,  // [E,2I,H] fp32 (fallback)
    const bf16* __restrict__ gup_b,   // [E,2I,H] bf16 (big)
    const int* __restrict__ etok, const float* __restrict__ ew,
    const int* __restrict__ cntpad,
    bf16* __restrict__ hsc) {         // [E*CAP, I] bf16
  __shared__ bf16 As[64 * 64];
  __shared__ bf16 Bg[128 * 64];
  __shared__ bf16 Bu[128 * 64];
  const int e  = blockIdx.z;
  const int m0 = blockIdx.x * 64;
  if (m0 >= cntpad[e]) return;
  const int n0 = blockIdx.y * 128;
  const int ebase = e * CAP;
  const int tid  = threadIdx.x;
  const int lane = tid & 63;
  const int wid  = tid >> 6;
  const int wm = (wid >> 1) * 32;
  const int wn = (wid & 1) * 64;
  const int lcol  = lane & 15;
  const int lquad = lane >> 4;
  // async staging: dest = tid*16B -> (row = tid>>3, chunk = tid&7); source col
  // compensates the xor swizzle so logical chunk = (tid&7)^(row&7).
  const int srow = tid >> 3;                       // 0..31
  const int swz  = ((tid & 7) ^ (srow & 7)) * 8;   // element offset in k

  int tokA0 = etok[ebase + m0 + srow];
  int tokA1 = etok[ebase + m0 + srow + 32];

  f32x4 accG[2][4], accU[2][4];
#pragma unroll
  for (int i = 0; i < 2; ++i)
#pragma unroll
    for (int j = 0; j < 4; ++j) {
      accG[i][j] = f32x4{0.f, 0.f, 0.f, 0.f};
      accU[i][j] = f32x4{0.f, 0.f, 0.f, 0.f};
    }

  for (int kk = 0; kk < HDIM; kk += 64) {
    __syncthreads();
    lds_load16(&As[tid * 8],        hid + (size_t)tokA0 * HDIM + kk + swz);
    lds_load16(&As[tid * 8 + 2048], hid + (size_t)tokA1 * HDIM + kk + swz);
    if constexpr (BBF) {
      const bf16* gB = gup_b + (size_t)e * (2 * IDIM) * HDIM + kk + swz;
#pragma unroll
      for (int i = 0; i < 4; ++i) {
        lds_load16(&Bg[tid * 8 + i * 2048], gB + (size_t)(n0 + srow + i * 32) * HDIM);
        lds_load16(&Bu[tid * 8 + i * 2048], gB + (size_t)(IDIM + n0 + srow + i * 32) * HDIM);
      }
    } else {
      const int r  = tid >> 4;             // 0..15
      const int c4 = (tid & 15) * 4;       // element col
      const int wb = (((c4 >> 3) ^ (r & 7)) * 8) + (c4 & 7);
      const float* gB = gup_f + (size_t)e * (2 * IDIM) * HDIM + kk + c4;
#pragma unroll
      for (int i = 0; i < 8; ++i) {
        float4 vg = *(const float4*)(gB + (size_t)(n0 + r + i * 16) * HDIM);
        float4 vu = *(const float4*)(gB + (size_t)(IDIM + n0 + r + i * 16) * HDIM);
        bf16x4 og, ou;
        og[0] = (bf16)vg.x; og[1] = (bf16)vg.y; og[2] = (bf16)vg.z; og[3] = (bf16)vg.w;
        ou[0] = (bf16)vu.x; ou[1] = (bf16)vu.y; ou[2] = (bf16)vu.z; ou[3] = (bf16)vu.w;
        *(bf16x4*)&Bg[(r + i * 16) * 64 + wb] = og;
        *(bf16x4*)&Bu[(r + i * 16) * 64 + wb] = ou;
      }
    }
    __syncthreads();
#pragma unroll
    for (int ks = 0; ks < 2; ++ks) {
      bf16x8 af[2], bg[4], bu[4];
#pragma unroll
      for (int mf = 0; mf < 2; ++mf) {
        int row = wm + mf * 16 + lcol;
        af[mf] = *(const bf16x8*)&As[row * 64 + (((ks * 4 + lquad) ^ (row & 7)) * 8)];
      }
#pragma unroll
      for (int nf = 0; nf < 4; ++nf) {
        int row = wn + nf * 16 + lcol;
        int off = row * 64 + (((ks * 4 + lquad) ^ (row & 7)) * 8);
        bg[nf] = *(const bf16x8*)&Bg[off];
        bu[nf] = *(const bf16x8*)&Bu[off];
      }
#pragma unroll
      for (int mf = 0; mf < 2; ++mf)
#pragma unroll
        for (int nf = 0; nf < 4; ++nf) {
          accG[mf][nf] = __builtin_amdgcn_mfma_f32_16x16x32_bf16(af[mf], bg[nf], accG[mf][nf], 0, 0, 0);
          accU[mf][nf] = __builtin_amdgcn_mfma_f32_16x16x32_bf16(af[mf], bu[nf], accU[mf][nf], 0, 0, 0);
        }
    }
  }
  // epilogue: C/D layout col=lane&15, row=lquad*4+reg
#pragma unroll
  for (int mf = 0; mf < 2; ++mf) {
#pragma unroll
    for (int rr = 0; rr < 4; ++rr) {
      const int erow = m0 + wm + mf * 16 + lquad * 4 + rr;
      const float wgt = ew[ebase + erow];
      bf16* orow = hsc + (size_t)(ebase + erow) * IDIM + n0 + wn;
#pragma unroll
      for (int nf = 0; nf < 4; ++nf) {
        float g = accG[mf][nf][rr];
        float u = accU[mf][nf][rr];
        float s = g / (1.f + __expf(-g));
        orow[nf * 16 + lcol] = (bf16)(s * u * wgt);
      }
    }
  }
}

// ---------------- GEMM2 (sparse): out[tok,h] += hsc[entry,:] . down[e,h,:] ----------------
// tile 64(entries) x 128(H), K=I=512, atomicAdd epilogue (~4 adds/address avg).

template <bool BBF>
__global__ __launch_bounds__(256, 4) void gemm2_kernel(
    const bf16* __restrict__ hsc,     // [E*CAP, I] bf16
    const float* __restrict__ down_f, // [E,H,I] fp32 (fallback)
    const bf16* __restrict__ down_b,  // [E,H,I] bf16 (big)
    const int* __restrict__ etok, const int* __restrict__ cntpad,
    float* __restrict__ out) {        // [T,H] fp32, pre-zeroed
  __shared__ bf16 As[64 * 64];
  __shared__ bf16 Bs[128 * 64];
  const int e  = blockIdx.z;
  const int m0 = blockIdx.x * 64;
  if (m0 >= cntpad[e]) return;
  const int n0 = blockIdx.y * 128;
  const int ebase = e * CAP;
  const int tid  = threadIdx.x;
  const int lane = tid & 63;
  const int wid  = tid >> 6;
  const int wm = (wid >> 1) * 32;
  const int wn = (wid & 1) * 64;
  const int lcol  = lane & 15;
  const int lquad = lane >> 4;
  const int srow = tid >> 3;
  const int swz  = ((tid & 7) ^ (srow & 7)) * 8;

  f32x4 acc[2][4];
#pragma unroll
  for (int i = 0; i < 2; ++i)
#pragma unroll
    for (int j = 0; j < 4; ++j) acc[i][j] = f32x4{0.f, 0.f, 0.f, 0.f};

  const bf16* gA = hsc + (size_t)(ebase + m0 + srow) * IDIM + swz;

  for (int kk = 0; kk < IDIM; kk += 64) {
    __syncthreads();
    lds_load16(&As[tid * 8],        gA + kk);
    lds_load16(&As[tid * 8 + 2048], gA + kk + (size_t)32 * IDIM);
    if constexpr (BBF) {
      const bf16* gB = down_b + (size_t)e * HDIM * IDIM + kk + swz;
#pragma unroll
      for (int i = 0; i < 4; ++i)
        lds_load16(&Bs[tid * 8 + i * 2048], gB + (size_t)(n0 + srow + i * 32) * IDIM);
    } else {
      const int r  = tid >> 4;
      const int c4 = (tid & 15) * 4;
      const int wb = (((c4 >> 3) ^ (r & 7)) * 8) + (c4 & 7);
      const float* gB = down_f + (size_t)e * HDIM * IDIM + kk + c4;
#pragma unroll
      for (int i = 0; i < 8; ++i) {
        float4 v = *(const float4*)(gB + (size_t)(n0 + r + i * 16) * IDIM);
        bf16x4 o;
        o[0] = (bf16)v.x; o[1] = (bf16)v.y; o[2] = (bf16)v.z; o[3] = (bf16)v.w;
        *(bf16x4*)&Bs[(r + i * 16) * 64 + wb] = o;
      }
    }
    __syncthreads();
#pragma unroll
    for (int ks = 0; ks < 2; ++ks) {
      bf16x8 af[2], bfv[4];
#pragma unroll
      for (int mf = 0; mf < 2; ++mf) {
        int row = wm + mf * 16 + lcol;
        af[mf] = *(const bf16x8*)&As[row * 64 + (((ks * 4 + lquad) ^ (row & 7)) * 8)];
      }
#pragma unroll
      for (int nf = 0; nf < 4; ++nf) {
        int row = wn + nf * 16 + lcol;
        bfv[nf] = *(const bf16x8*)&Bs[row * 64 + (((ks * 4 + lquad) ^ (row & 7)) * 8)];
      }
#pragma unroll
      for (int mf = 0; mf < 2; ++mf)
#pragma unroll
        for (int nf = 0; nf < 4; ++nf)
          acc[mf][nf] = __builtin_amdgcn_mfma_f32_16x16x32_bf16(af[mf], bfv[nf], acc[mf][nf], 0, 0, 0);
    }
  }
#pragma unroll
  for (int mf = 0; mf < 2; ++mf) {
#pragma unroll
    for (int rr = 0; rr < 4; ++rr) {
      const int erow = m0 + wm + mf * 16 + lquad * 4 + rr;
      const int tok = etok[ebase + erow];
      float* orow = out + (size_t)tok * HDIM + n0 + wn;
#pragma unroll
      for (int nf = 0; nf < 4; ++nf)
        atomicAdd(&orow[nf * 16 + lcol], acc[mf][nf][rr]);
    }
  }
}

// ---------------- launch ----------------

extern "C" void kernel_launch(void* const* d_in, const int* in_sizes, int n_in,
                              void* d_out, int out_size, void* d_ws, size_t ws_size,
                              hipStream_t stream) {
  const float* hid_f  = (const float*)d_in[0];
  const int*   idx    = (const int*)d_in[1];
  const float* tw     = (const float*)d_in[2];
  const float* gup_f  = (const float*)d_in[3];
  const float* down_f = (const float*)d_in[4];
  float* out = (float*)d_out;

  uint8_t* ws = (uint8_t*)d_ws;
  size_t off = 0;
  bf16* hid_b = (bf16*)(ws + off);           off += (size_t)T_TOK * HDIM * 2;
  int*  etok  = (int*)(ws + off);            off += (size_t)NEXP * CAP * 4;
  float* ewt  = (float*)(ws + off);          off += (size_t)NEXP * CAP * 4;
  int*  cntpad = (int*)(ws + off);           off += 256;
  bf16* hsc   = (bf16*)(ws + off);           off += (size_t)NEXP * CAP * IDIM * 2;
  bf16* gup_b = (bf16*)(ws + off);
  size_t gup_bytes = (size_t)NEXP * 2 * IDIM * HDIM * 2;
  bf16* down_b = (bf16*)(ws + off + gup_bytes);
  size_t need_big = off + gup_bytes + (size_t)NEXP * HDIM * IDIM * 2;
  const bool big = (ws_size >= need_big);

  hipMemsetAsync(d_out, 0, (size_t)T_TOK * HDIM * sizeof(float), stream);
  routing_kernel<<<dim3(1), dim3(1024), 0, stream>>>(idx, tw, etok, ewt, cntpad);
  cvt_kernel<<<dim3(T_TOK * HDIM / 4 / 256), dim3(256), 0, stream>>>(hid_f, hid_b, T_TOK * HDIM / 4);

  if (big) {
    cvt_kernel<<<dim3(NEXP * 2 * IDIM * HDIM / 4 / 256), dim3(256), 0, stream>>>(
        gup_f, gup_b, NEXP * 2 * IDIM * HDIM / 4);
    cvt_kernel<<<dim3(NEXP * HDIM * IDIM / 4 / 256), dim3(256), 0, stream>>>(
        down_f, down_b, NEXP * HDIM * IDIM / 4);
    gemm1_kernel<true><<<dim3(CAP / 64, IDIM / 128, NEXP), dim3(256), 0, stream>>>(
        hid_b, nullptr, gup_b, etok, ewt, cntpad, hsc);
    gemm2_kernel<true><<<dim3(CAP / 64, HDIM / 128, NEXP), dim3(256), 0, stream>>>(
        hsc, nullptr, down_b, etok, cntpad, out);
  } else {
    gemm1_kernel<false><<<dim3(CAP / 64, IDIM / 128, NEXP), dim3(256), 0, stream>>>(
        hid_b, gup_f, nullptr, etok, ewt, cntpad, hsc);
    gemm2_kernel<false><<<dim3(CAP / 64, HDIM / 128, NEXP), dim3(256), 0, stream>>>(
        hsc, down_f, nullptr, etok, cntpad, out);
  }
}